// Round 16
// baseline (195.783 us; speedup 1.0000x reference)
//
#include <hip/hip_runtime.h>
#include <hip/hip_bf16.h>
#include <math.h>

#define D 64
#define K_CODES 8192
#define M_QUERIES 32768
#define SLICES 8
#define CODES_PER_SLICE (K_CODES / SLICES)  // 1024
#define CHUNK 32
#define NCHUNK (CODES_PER_SLICE / CHUNK)    // 32 chunks per slice
#define QPB 128                              // queries per block = 4 waves * 32
#define TAU_V 4e-3f                          // gap threshold in v units

typedef __attribute__((ext_vector_type(8))) short bf16x8;
typedef __attribute__((ext_vector_type(4))) float f32x4;
typedef __attribute__((ext_vector_type(16))) float f32x16;

__device__ __forceinline__ unsigned short f2bf(float x) {
    __hip_bfloat16 h = __float2bfloat16(x);
    return *reinterpret_cast<unsigned short*>(&h);
}
__device__ __forceinline__ float bf2f(unsigned short s) {
    __hip_bfloat16 h;
    *reinterpret_cast<unsigned short*>(&h) = s;
    return __bfloat162float(h);
}
__device__ __forceinline__ void gld_lds16(const void* g, void* l) {
    __builtin_amdgcn_global_load_lds(
        (const __attribute__((address_space(1))) void*)g,
        (__attribute__((address_space(3))) void*)l, 16, 0, 0);
}
__device__ __forceinline__ void gld_lds4(const void* g, void* l) {
    __builtin_amdgcn_global_load_lds(
        (const __attribute__((address_space(1))) void*)g,
        (__attribute__((address_space(3))) void*)l, 4, 0, 0);
}

// ---- K0: split emb into bf16 hi/lo in MFMA-FRAGMENT order, 32-code chunks ----
__global__ __launch_bounds__(256) void k0_split(const float* __restrict__ emb,
                                                unsigned short* __restrict__ e_hi,
                                                unsigned short* __restrict__ e_lo,
                                                float* __restrict__ halfee,
                                                int* __restrict__ ws_cnt) {
    const int t = threadIdx.x;
    const int grp = blockIdx.x;                 // 64-code group
    if (grp == 0 && t == 0) *ws_cnt = 0;
    const int u = t & 7;
#pragma unroll
    for (int it = 0; it < 2; ++it) {
        const int r = (t >> 3) + it * 32;       // code within 64-group
        const int code = grp * 64 + r;
        const float* src = emb + ((size_t)code * 64 + u * 8);
        float4 f0 = *(const float4*)(src);
        float4 f1 = *(const float4*)(src + 4);
        float f[8] = {f0.x, f0.y, f0.z, f0.w, f1.x, f1.y, f1.z, f1.w};
        bf16x8 h, lo;
        float s = 0.f;
#pragma unroll
        for (int j = 0; j < 8; ++j) {
            float e = f[j];
            s += e * e;
            unsigned short hh = f2bf(e);
            h[j]  = (short)hh;
            lo[j] = (short)f2bf(e - bf2f(hh));
        }
        const int c32 = code >> 5, r32 = code & 31;
        size_t off = (size_t)c32 * 4096 + (size_t)(u * 32 + r32) * 16;
        *(bf16x8*)((char*)e_hi + off) = h;
        *(bf16x8*)((char*)e_lo + off) = lo;
        s += __shfl_xor(s, 1);
        s += __shfl_xor(s, 2);
        s += __shfl_xor(s, 4);
        if (u == 0) halfee[code] = 0.5f * s + 128.0f;
    }
}

// ---- K1: 32x32x16 MFMA scoring, deferred tree-TOP2 (phase de-serialization) ----
// r15 diagnosis: pipes used serially (MfmaUtil==VALUBusy==42%); barrier
// lockstep aligns all waves' MFMA phase then TOP2 phase. Fix: acc double-
// buffer (accE/accO) -> TOP2 of chunk c-1 runs interleaved with chunk c's
// MFMA issue (independent -> compiler co-schedules); tree-TOP2 (med3 merge)
// cuts the serial compare chain ~4x. 32 q/wave keeps VGPR ~100 (no spill).
__global__ __launch_bounds__(256, 1) void k1_mfma(const float* __restrict__ z,
                                                  const unsigned short* __restrict__ e_hi,
                                                  const unsigned short* __restrict__ e_lo,
                                                  const float* __restrict__ halfee,
                                                  float4* __restrict__ ws_part) {
    __shared__ __align__(16) unsigned short ldshi[2][CHUNK * 64];  // 4KB each buf
    __shared__ __align__(16) unsigned short ldslo[2][CHUNK * 64];
    __shared__ __align__(16) float ldshe[2][CHUNK];                // 128B each

    const int tid = threadIdx.x;
    const int wid = tid >> 6;    // 0..3
    const int l   = tid & 63;
    const int col = l & 31;
    const int hi  = l >> 5;
    const int slice = blockIdx.y;
    const int chunk0 = slice * NCHUNK;   // global 32-chunk base
    const int cbase0 = slice * CODES_PER_SLICE;

    // this wave's 32 queries -> negated bf16 hi/lo B-fragments
    const int qw0 = blockIdx.x * QPB + wid * 32;
    const int qrow = qw0 + col;
    bf16x8 qh[4], ql[4];
#pragma unroll
    for (int kk = 0; kk < 4; ++kk) {
        const float* src = z + (size_t)qrow * D + kk * 16 + hi * 8;
        float4 f0 = *(const float4*)(src);
        float4 f1 = *(const float4*)(src + 4);
        float f[8] = {f0.x, f0.y, f0.z, f0.w, f1.x, f1.y, f1.z, f1.w};
        bf16x8 h, lo;
#pragma unroll
        for (int j = 0; j < 8; ++j) {
            float x = -f[j];
            unsigned short hh = f2bf(x);
            float r = x - bf2f(hh);
            h[j]  = (short)hh;
            lo[j] = (short)f2bf(r);
        }
        qh[kk] = h;
        ql[kk] = lo;
    }

    float g1 = 1e30f, g2 = 1e30f;
    int   gi = 0x7fffffff;

// staging: wave w stages 1KB hi + 1KB lo; lanes 0-31 of wave 0 stage 128B he.
#define STAGE(buf, c1)                                                           \
    {                                                                            \
        size_t cb = (size_t)(chunk0 + (c1)) * 4096 + wid * 1024 + l * 16;        \
        gld_lds16((const char*)e_hi + cb, (char*)&ldshi[buf][0] + wid * 1024);   \
        gld_lds16((const char*)e_lo + cb, (char*)&ldslo[buf][0] + wid * 1024);   \
        if (tid < 32)                                                            \
            gld_lds4((const char*)halfee + (size_t)(chunk0 + (c1)) * 128 + tid * 4, \
                     (char*)&ldshe[buf][0]);                                     \
    }

// 12 MFMA (hi.qh + hi.ql + lo.qh per kk), C-in preloaded with he'.
#define MFMA_CHUNK(bufc, acc)                                                    \
    {                                                                            \
        const char*  bh  = (const char*)ldshi[bufc];                             \
        const char*  bl  = (const char*)ldslo[bufc];                             \
        const float* bhe = ldshe[bufc];                                          \
        _Pragma("unroll") for (int g4 = 0; g4 < 4; ++g4) {                       \
            f32x4 he4 = *(const f32x4*)(bhe + g4 * 8 + 4 * hi);                  \
            _Pragma("unroll") for (int j = 0; j < 4; ++j)                        \
                acc[g4 * 4 + j] = he4[j];                                        \
        }                                                                        \
        _Pragma("unroll") for (int kk = 0; kk < 4; ++kk) {                       \
            int a0 = ((kk * 2 + hi) * 32 + col) * 16;   /* lane-contiguous */    \
            bf16x8 ah = *(const bf16x8*)(bh + a0);                               \
            bf16x8 al = *(const bf16x8*)(bl + a0);                               \
            acc = __builtin_amdgcn_mfma_f32_32x32x16_bf16(ah, qh[kk], acc, 0, 0, 0); \
            acc = __builtin_amdgcn_mfma_f32_32x32x16_bf16(ah, ql[kk], acc, 0, 0, 0); \
            acc = __builtin_amdgcn_mfma_f32_32x32x16_bf16(al, qh[kk], acc, 0, 0, 0); \
        }                                                                        \
    }

// tree top-2 over the 16 acc values; merge rule: second-of-union =
// med3(m1a, m1b, min(m2a, m2b)). 4-bit pos packed in mantissa LSBs.
#define TOP2T(acc, cbase)                                                        \
    {                                                                            \
        float t1[8], t2[8];                                                      \
        _Pragma("unroll") for (int i = 0; i < 8; ++i) {                          \
            float va = __int_as_float((__float_as_int(acc[2 * i])     & 0xFFFFFFF0) | (2 * i));     \
            float vb = __int_as_float((__float_as_int(acc[2 * i + 1]) & 0xFFFFFFF0) | (2 * i + 1)); \
            t1[i] = fminf(va, vb);                                               \
            t2[i] = fmaxf(va, vb);                                               \
        }                                                                        \
        _Pragma("unroll") for (int s = 4; s > 0; s >>= 1) {                      \
            _Pragma("unroll") for (int i = 0; i < s; ++i) {                      \
                float m2c = fminf(t2[i], t2[i + s]);                             \
                t2[i] = __builtin_amdgcn_fmed3f(t1[i], t1[i + s], m2c);          \
                t1[i] = fminf(t1[i], t1[i + s]);                                 \
            }                                                                    \
        }                                                                        \
        float m1p = t1[0], m2p = t2[0];                                          \
        int p1 = __float_as_int(m1p) & 15;                                       \
        int code = (cbase) + (p1 & 3) + 8 * (p1 >> 2) + 4 * hi;                  \
        bool lt = m1p < g1;                                                      \
        g2 = fminf(lt ? g1 : g2, lt ? m2p : m1p);                                \
        g1 = lt ? m1p : g1;                                                      \
        gi = lt ? code : gi;                                                     \
    }

    f32x16 accE, accO;

    STAGE(0, 0);
    __syncthreads();
    STAGE(1, 1);
    MFMA_CHUNK(0, accE);                 // chunk 0
    __syncthreads();
    for (int cc = 1; cc + 1 < NCHUNK; cc += 2) {
        STAGE(0, cc + 1);                // chunk cc+1 -> buf0
        MFMA_CHUNK(1, accO);             // chunk cc
        TOP2T(accE, cbase0 + (cc - 1) * CHUNK);   // finish chunk cc-1 (overlaps MFMA)
        __syncthreads();
        if (cc + 2 < NCHUNK) STAGE(1, cc + 2);    // chunk cc+2 -> buf1
        MFMA_CHUNK(0, accE);             // chunk cc+1
        TOP2T(accO, cbase0 + cc * CHUNK);         // finish chunk cc
        __syncthreads();
    }
    MFMA_CHUNK(1, accO);                 // chunk NCHUNK-1
    TOP2T(accE, cbase0 + (NCHUNK - 2) * CHUNK);
    TOP2T(accO, cbase0 + (NCHUNK - 1) * CHUNK);

    // lanes l and l^32 share a query column, hold disjoint code rows
    {
        float o1 = __shfl_xor(g1, 32);
        float o2 = __shfl_xor(g2, 32);
        int   oi = __shfl_xor(gi, 32);
        bool  take = (o1 < g1) || (o1 == g1 && oi < gi);
        float n2   = take ? fminf(o2, g1) : fminf(g2, o1);
        g1 = take ? o1 : g1;
        gi = take ? oi : gi;
        g2 = n2;
        if (l < 32) {
            int q = qw0 + col;
            ws_part[(size_t)q * SLICES + slice] =
                make_float4(g1, g2, __int_as_float(gi), 0.f);
        }
    }
#undef STAGE
#undef MFMA_CHUNK
#undef TOP2T
}

// ---- K1b: merge slices, flag near-ties ----
__global__ __launch_bounds__(256) void k1b_merge(const float4* __restrict__ ws_part,
                                                 int* __restrict__ ws_idx,
                                                 int* __restrict__ ws_cnt,
                                                 int* __restrict__ ws_list) {
    int q = blockIdx.x * blockDim.x + threadIdx.x;
    float m1 = 1e30f, m2 = 1e30f;
    int   i1 = 0x7fffffff;
#pragma unroll
    for (int s = 0; s < SLICES; ++s) {
        float4 p = ws_part[(size_t)q * SLICES + s];
        float v1 = p.x, v2 = p.y;
        int   vi = __float_as_int(p.z);
        if (v1 < m1 || (v1 == m1 && vi < i1)) { m2 = fminf(m1, v2); m1 = v1; i1 = vi; }
        else                                  { m2 = fminf(m2, v1); }
    }
    ws_idx[q] = i1;
    if (m2 - m1 < TAU_V) {
        int r = atomicAdd(ws_cnt, 1);
        ws_list[r] = q;
    }
}

// ---- K2: fp64 exact rescan for near-tie queries ----
__global__ __launch_bounds__(256) void k2_rescue(const float* __restrict__ z,
                                                 const float* __restrict__ emb,
                                                 const int* __restrict__ ws_cnt,
                                                 const int* __restrict__ ws_list,
                                                 int* __restrict__ ws_idx) {
    __shared__ float  zrow[D];
    __shared__ double rv[256];
    __shared__ int    ri[256];
    const int cnt = *ws_cnt;
    for (int r = blockIdx.x; r < cnt; r += gridDim.x) {
        const int q = ws_list[r];
        __syncthreads();
        if (threadIdx.x < D) zrow[threadIdx.x] = z[(size_t)q * D + threadIdx.x];
        __syncthreads();
        double best = 1e300;
        int    bi   = 0x7fffffff;
        for (int c = threadIdx.x; c < K_CODES; c += 256) {
            const float4* er = (const float4*)(emb + (size_t)c * D);
            double acc = 0.0;
#pragma unroll
            for (int k = 0; k < 16; ++k) {
                float4 e  = er[k];
                double d0 = (double)zrow[4 * k + 0] - (double)e.x;
                double d1 = (double)zrow[4 * k + 1] - (double)e.y;
                double d2 = (double)zrow[4 * k + 2] - (double)e.z;
                double d3 = (double)zrow[4 * k + 3] - (double)e.w;
                acc += d0 * d0 + d1 * d1 + d2 * d2 + d3 * d3;
            }
            if (acc < best) { best = acc; bi = c; }
        }
        rv[threadIdx.x] = best;
        ri[threadIdx.x] = bi;
        __syncthreads();
        for (int s = 128; s > 0; s >>= 1) {
            if (threadIdx.x < s) {
                double ov = rv[threadIdx.x + s];
                int    oi = ri[threadIdx.x + s];
                if (ov < rv[threadIdx.x] || (ov == rv[threadIdx.x] && oi < ri[threadIdx.x])) {
                    rv[threadIdx.x] = ov;
                    ri[threadIdx.x] = oi;
                }
            }
            __syncthreads();
        }
        if (threadIdx.x == 0) ws_idx[q] = ri[0];
        __syncthreads();
    }
}

// ---- K3: gather z_q, emit idx as float, per-block loss partials ----
__global__ __launch_bounds__(256) void k3_gather(const float* __restrict__ emb,
                                                 const float* __restrict__ z,
                                                 const int* __restrict__ ws_idx,
                                                 float* __restrict__ out,
                                                 float* __restrict__ partial) {
    __shared__ float sb[256];
    int g = blockIdx.x * 256 + threadIdx.x;
    int q = g >> 6, d = g & 63;
    int id = ws_idx[q];
    float e = emb[(size_t)id * D + d];
    out[g] = e;
    if (d == 0) out[(size_t)M_QUERIES * D + q] = (float)id;
    float df = e - z[g];
    sb[threadIdx.x] = df * df;
    __syncthreads();
    for (int s = 128; s > 0; s >>= 1) {
        if (threadIdx.x < s) sb[threadIdx.x] += sb[threadIdx.x + s];
        __syncthreads();
    }
    if (threadIdx.x == 0) partial[blockIdx.x] = sb[0];
}

// ---- K4: final loss reduce ----
__global__ __launch_bounds__(256) void k4_loss(const float* __restrict__ partial,
                                               float* __restrict__ out) {
    __shared__ double sb[256];
    double s = 0.0;
    for (int i = threadIdx.x; i < (M_QUERIES * D) / 256; i += 256) s += (double)partial[i];
    sb[threadIdx.x] = s;
    __syncthreads();
    for (int st = 128; st > 0; st >>= 1) {
        if (threadIdx.x < st) sb[threadIdx.x] += sb[threadIdx.x + st];
        __syncthreads();
    }
    if (threadIdx.x == 0)
        out[(size_t)M_QUERIES * D + M_QUERIES] =
            (float)(1.25 * sb[0] / (double)((size_t)M_QUERIES * D));
}

extern "C" void kernel_launch(void* const* d_in, const int* in_sizes, int n_in,
                              void* d_out, int out_size, void* d_ws, size_t ws_size,
                              hipStream_t stream) {
    const float* z   = (const float*)d_in[0];
    const float* emb = (const float*)d_in[1];
    float* out = (float*)d_out;
    char*  ws  = (char*)d_ws;

    unsigned short* e_hi    = (unsigned short*)(ws);                    // 1 MB
    unsigned short* e_lo    = (unsigned short*)(ws + 1048576);          // 1 MB
    float*          halfee  = (float*)(ws + 2097152);                   // 32 KB
    float4*         ws_part = (float4*)(ws + 2129920);                  // 4 MB (8 slices)
    int*            ws_idx  = (int*)(ws + 2129920 + 4194304);           // 128 KB
    int*            ws_cnt  = (int*)(ws + 2129920 + 4194304 + 131072);  // 64 B
    int*            ws_list = (int*)(ws + 2129920 + 4194304 + 131136);  // 128 KB
    float*          partial = (float*)(ws + 2129920 + 4194304 + 262208);// 32 KB

    k0_split<<<K_CODES / 64, 256, 0, stream>>>(emb, e_hi, e_lo, halfee, ws_cnt);

    dim3 g1(M_QUERIES / QPB, SLICES);   // (256, 8) = 2048 blocks of 256 threads
    k1_mfma<<<g1, 256, 0, stream>>>(z, e_hi, e_lo, halfee, ws_part);

    k1b_merge<<<M_QUERIES / 256, 256, 0, stream>>>(ws_part, ws_idx, ws_cnt, ws_list);

    k2_rescue<<<256, 256, 0, stream>>>(z, emb, ws_cnt, ws_list, ws_idx);

    k3_gather<<<(M_QUERIES * D) / 256, 256, 0, stream>>>(emb, z, ws_idx, out, partial);

    k4_loss<<<1, 256, 0, stream>>>(partial, out);
}